// Round 15
// baseline (278.995 us; speedup 1.0000x reference)
//
#include <hip/hip_runtime.h>
#include <stdint.h>

#define NBLOCKS 256
#define TROWS 64
#define B_FRAGS 94                        // frags 94..127 stream from L2
#define XT0_OFF (B_FRAGS * 1024)          // 96256
#define XT1_OFF (XT0_OFF + 32768)         // 129024
#define SPART_OFF (XT1_OFF + 32768)       // 161792
#define SMEM_BYTES (SPART_OFF + 1024)     // 162816 <= 163840

typedef __attribute__((ext_vector_type(8))) short bfrag_t;
typedef __attribute__((ext_vector_type(4))) float f32x4;
typedef __attribute__((ext_vector_type(2))) unsigned int u32x2;

static __device__ __forceinline__ unsigned short f2bf(float f) {
  unsigned int u = __float_as_uint(f);
  u += 0x7fffu + ((u >> 16) & 1u);   // RNE
  return (unsigned short)(u >> 16);
}

static __device__ __forceinline__ float tanh_fast(float s) {
  float e = __builtin_exp2f(s * 2.8853900817779268f);
  float r = __builtin_amdgcn_rcpf(1.f + e);
  return __builtin_fmaf(-2.f, r, 1.f);
}

// readlane for floats: BIT-cast (int builtin; float would value-truncate — r4 bug)
static __device__ __forceinline__ float readlane_f(float v, int l) {
  return __uint_as_float(__builtin_amdgcn_readlane(__float_as_uint(v), l));
}

static __device__ __forceinline__ bfrag_t pack8(f32x4 a, f32x4 b) {
  union { bfrag_t v; unsigned int u[4]; } r;
  asm("v_cvt_pk_bf16_f32 %0, %1, %2" : "=v"(r.u[0]) : "v"(a[0]), "v"(a[1]));
  asm("v_cvt_pk_bf16_f32 %0, %1, %2" : "=v"(r.u[1]) : "v"(a[2]), "v"(a[3]));
  asm("v_cvt_pk_bf16_f32 %0, %1, %2" : "=v"(r.u[2]) : "v"(b[0]), "v"(b[1]));
  asm("v_cvt_pk_bf16_f32 %0, %1, %2" : "=v"(r.u[3]) : "v"(b[2]), "v"(b[3]));
  return r.v;
}

#define GLD16(gp, lp) __builtin_amdgcn_global_load_lds( \
    (const __attribute__((address_space(1))) void*)(gp), \
    (__attribute__((address_space(3))) void*)(lp), 16, 0, 0)

// raw barrier draining LDS ops only; global reg-loads stay in flight
#define BAR_LGKM() do { \
  asm volatile("s_waitcnt lgkmcnt(0)" ::: "memory"); \
  __builtin_amdgcn_s_barrier(); \
  asm volatile("" ::: "memory"); } while (0)

// Pre-swizzle W1 (f32 [256][256], k-major) into MFMA B-fragment order, bf16.
// W1f[((cc*8+kk)*64 + lane)*8 + j] = bf16(W1[kk*32 + 8*(lane>>4) + j][cc*16 + (lane&15)])
__global__ void prep_w1_kernel(const float* __restrict__ W1, unsigned short* __restrict__ W1f) {
  const int bx = blockIdx.x;   // cc*8 + kk, 0..127
  const int l = threadIdx.x;   // 0..63
  const int cc = bx >> 3, kk = bx & 7;
  const int h = cc * 16 + (l & 15);
  const int kbase = kk * 32 + ((l >> 4) << 3);
  bfrag_t pk;
#pragma unroll
  for (int j = 0; j < 8; ++j) pk[j] = (short)f2bf(W1[(size_t)(kbase + j) * 256 + h]);
  *(bfrag_t*)(W1f + (size_t)(bx * 64 + l) * 8) = pk;
}

__attribute__((amdgpu_flat_work_group_size(512, 512), amdgpu_waves_per_eu(2, 2)))
__global__ void attnpool_kernel(const float* __restrict__ x,
                                const int* __restrict__ batch,
                                const unsigned short* __restrict__ W1f,
                                const float* __restrict__ b1,
                                const float* __restrict__ W2,
                                const float* __restrict__ b2,
                                float* __restrict__ out,   // raw weighted sums (zeroed)
                                float* __restrict__ Zp,    // softmax denominator (zeroed)
                                int N, int base, int rem) {
  extern __shared__ char smem[];
  char* Bl = smem;                           // B frags 0..93, frag-linear
  float* spart = (float*)(smem + SPART_OFF); // [4 cgr][64 rows]

  const int t = threadIdx.x;
  const int lane = t & 63;
  const int wv = t >> 6;        // 0..7
  const int rg = wv & 1;        // row half: rows rg*32..+31
  const int cgr = wv >> 1;      // cc quad: cc cgr*4..+3
  const int l15 = lane & 15;
  const int hi = lane >> 4;

  const int blk = blockIdx.x;
  const int cnt = base + (blk < rem ? 1 : 0);
  const int tile0 = blk * base + min(blk, rem);

  // ---- B -> LDS (frag-linear via GLD16; frags >= B_FRAGS stay in L2) ----
#pragma unroll
  for (int i = 0; i < 12; ++i) {
    const int f = wv * 12 + i;
    if (f < B_FRAGS) GLD16(W1f + (size_t)f * 512 + lane * 8, Bl + f * 1024);
  }

  // per-lane constants for my 4 cc's
  float b1v[4], w2v[4];
#pragma unroll
  for (int c = 0; c < 4; ++c) {
    b1v[c] = b1[(cgr * 4 + c) * 16 + l15];
    w2v[c] = W2[(cgr * 4 + c) * 16 + l15];
  }
  const float b2c = b2[0];

  // ---- cooperative 1-deep reg staging: 512 threads stage 64 rows ----
  const int srow = t >> 5;    // 0..15
  const int soct = t & 31;
  f32x4 sreg[8];
  auto issue_loads = [&](int tile) {
#pragma unroll
    for (int p = 0; p < 4; ++p) {
      const int row = p * 16 + srow;
      const int rgb = min(tile * TROWS + row, N - 1);
      const float* s = x + (size_t)rgb * 256 + soct * 8;
      sreg[2 * p] = *(const f32x4*)s;
      sreg[2 * p + 1] = *(const f32x4*)(s + 4);
    }
  };
  auto write_tile = [&](char* buf) {
#pragma unroll
    for (int p = 0; p < 4; ++p) {
      const int row = p * 16 + srow;
      *(bfrag_t*)(buf + row * 512 + ((soct * 16) ^ ((row & 7) << 4))) =
          pack8(sreg[2 * p], sreg[2 * p + 1]);
    }
  };

  float zacc = 0.f;
  f32x4 pacc = {0.f, 0.f, 0.f, 0.f};
  int gcur = -1;

  auto flush = [&]() {
    float* po = out + (size_t)gcur * 256 + lane * 4;
    atomicAdd(po + 0, pacc[0]); atomicAdd(po + 1, pacc[1]);
    atomicAdd(po + 2, pacc[2]); atomicAdd(po + 3, pacc[3]);
    pacc[0] = pacc[1] = pacc[2] = pacc[3] = 0.f;
  };

  // prologue: stage tile0 (vmcnt wait in write_tile also drains B's GLD16s — FIFO)
  issue_loads(tile0);
  write_tile(smem + XT0_OFF);
  BAR_LGKM();

  for (int tt = 0; tt < cnt; ++tt) {
    const int tile = tile0 + tt;
    const int R0 = tile * TROWS;
    char* xc = smem + ((tt & 1) ? XT1_OFF : XT0_OFF);
    char* xn = smem + ((tt & 1) ? XT0_OFF : XT1_OFF);

    if (tt + 1 < cnt) issue_loads(tile + 1);   // in flight across whole body

    // ---- score: kk-outer; one B-read feeds 32 rows (A0,A1) ----
    f32x4 acc[4][2] = {};
    const int arow0 = rg * 32 + l15;
    const int sw = (l15 & 7) << 4;             // (arow0+16)&7 == arow0&7
#pragma unroll
    for (int kk = 0; kk < 8; ++kk) {
      const int co = (kk * 64 + hi * 16) ^ sw;
      const bfrag_t A0 = *(const bfrag_t*)(xc + arow0 * 512 + co);
      const bfrag_t A1 = *(const bfrag_t*)(xc + (arow0 + 16) * 512 + co);
#pragma unroll
      for (int c = 0; c < 4; ++c) {
        const int frag = (cgr * 4 + c) * 8 + kk;
        bfrag_t Bk;
        if (frag < B_FRAGS)    // wave-uniform branch
          Bk = *(const bfrag_t*)(Bl + frag * 1024 + lane * 16);
        else
          Bk = *(const bfrag_t*)(W1f + (size_t)frag * 512 + lane * 8);
        acc[c][0] = __builtin_amdgcn_mfma_f32_16x16x32_bf16(A0, Bk, acc[c][0], 0, 0, 0);
        acc[c][1] = __builtin_amdgcn_mfma_f32_16x16x32_bf16(A1, Bk, acc[c][1], 0, 0, 0);
      }
    }

    // ---- tanh epilogue + 16-lane reduce; partial for my cc-quad ----
    float s0v[4] = {0.f, 0.f, 0.f, 0.f};
    float s1v[4] = {0.f, 0.f, 0.f, 0.f};
#pragma unroll
    for (int c = 0; c < 4; ++c)
#pragma unroll
      for (int r = 0; r < 4; ++r) {
        s0v[r] += tanh_fast(acc[c][0][r] + b1v[c]) * w2v[c];
        s1v[r] += tanh_fast(acc[c][1][r] + b1v[c]) * w2v[c];
      }
#pragma unroll
    for (int r = 0; r < 4; ++r) {
      float v0 = s0v[r], v1 = s1v[r];
      v0 += __shfl_xor(v0, 1); v0 += __shfl_xor(v0, 2);
      v0 += __shfl_xor(v0, 4); v0 += __shfl_xor(v0, 8);
      v1 += __shfl_xor(v1, 1); v1 += __shfl_xor(v1, 2);
      v1 += __shfl_xor(v1, 4); v1 += __shfl_xor(v1, 8);
      s0v[r] = v0; s1v[r] = v1;
    }
    if (l15 == 0) {
#pragma unroll
      for (int r = 0; r < 4; ++r) {
        spart[cgr * 64 + rg * 32 + hi * 4 + r] = s0v[r];
        spart[cgr * 64 + rg * 32 + 16 + hi * 4 + r] = s1v[r];
      }
    }
    BAR_LGKM();   // SYNC1: all 4 partials visible

    // ---- w for my pool rows (wv*8..+7): sum 4 partials, exp ----
    const int prow = wv * 8 + (lane & 7);
    float wlane;
    {
      float v = spart[((lane >> 3) & 3) * 64 + prow];
      v += __shfl_xor(v, 8);
      v += __shfl_xor(v, 16);
      wlane = (R0 + prow < N) ? __expf(v + b2c) : 0.f;
    }
    {
      float zv = (lane < 8) ? wlane : 0.f;
      zv += __shfl_xor(zv, 1);  zv += __shfl_xor(zv, 2);  zv += __shfl_xor(zv, 4);
      zv += __shfl_xor(zv, 8);  zv += __shfl_xor(zv, 16); zv += __shfl_xor(zv, 32);
      zacc += zv;
    }
    int bid = batch[min(R0 + prow, N - 1)];

    // ---- pool my 8 rows from xc; lane owns bf16 cols 4*lane..+3 ----
    const int g_first = __builtin_amdgcn_readlane(bid, 0);
    const int g_last = __builtin_amdgcn_readlane(bid, 7);
    if (g_first != gcur) { if (gcur >= 0) flush(); gcur = g_first; }
    const int rowb = wv * 8;
    if (g_first == g_last) {
#pragma unroll
      for (int r = 0; r < 8; ++r) {
        const float wr = readlane_f(wlane, r);
        const int row = rowb + r;
        const u32x2 v = *(const u32x2*)(xc + row * 512 + ((lane * 8) ^ ((row & 7) << 4)));
        pacc[0] = __builtin_fmaf(wr, __uint_as_float(v[0] << 16), pacc[0]);
        pacc[1] = __builtin_fmaf(wr, __uint_as_float(v[0] & 0xffff0000u), pacc[1]);
        pacc[2] = __builtin_fmaf(wr, __uint_as_float(v[1] << 16), pacc[2]);
        pacc[3] = __builtin_fmaf(wr, __uint_as_float(v[1] & 0xffff0000u), pacc[3]);
      }
    } else {
      for (int r = 0; r < 8; ++r) {
        const int g = __builtin_amdgcn_readlane(bid, r);
        if (g != gcur) { flush(); gcur = g; }
        const float wr = readlane_f(wlane, r);
        const int row = rowb + r;
        const u32x2 v = *(const u32x2*)(xc + row * 512 + ((lane * 8) ^ ((row & 7) << 4)));
        pacc[0] = __builtin_fmaf(wr, __uint_as_float(v[0] << 16), pacc[0]);
        pacc[1] = __builtin_fmaf(wr, __uint_as_float(v[0] & 0xffff0000u), pacc[1]);
        pacc[2] = __builtin_fmaf(wr, __uint_as_float(v[1] << 16), pacc[2]);
        pacc[3] = __builtin_fmaf(wr, __uint_as_float(v[1] & 0xffff0000u), pacc[3]);
      }
    }

    // ---- write next tile into the other buffer (overlaps: no reader of xn) ----
    if (tt + 1 < cnt) write_tile(xn);
    BAR_LGKM();   // SYNC2: pool reads (xc) + writes (xn) ordered for next body
  }

  if (gcur >= 0) flush();
  if (lane == 0 && zacc != 0.f) atomicAdd(Zp, zacc);
}

__global__ void finalize_kernel(float* __restrict__ out, const float* __restrict__ Zp, int n4) {
  const int i = blockIdx.x * blockDim.x + threadIdx.x;
  if (i < n4) {
    const float zi = 1.f / Zp[0];
    f32x4* p = (f32x4*)out;
    f32x4 v = p[i];
    v[0] *= zi; v[1] *= zi; v[2] *= zi; v[3] *= zi;
    p[i] = v;
  }
}

extern "C" void kernel_launch(void* const* d_in, const int* in_sizes, int n_in,
                              void* d_out, int out_size, void* d_ws, size_t ws_size,
                              hipStream_t stream) {
  const float* x  = (const float*)d_in[0];
  const int* batch = (const int*)d_in[1];
  const float* W1 = (const float*)d_in[2];
  const float* b1 = (const float*)d_in[3];
  const float* W2 = (const float*)d_in[4];
  const float* b2 = (const float*)d_in[5];
  float* out = (float*)d_out;
  const int N = in_sizes[1];

  unsigned short* W1f = (unsigned short*)d_ws;          // 128 KB
  float* Zp = (float*)((char*)d_ws + 131072);           // 4 B

  static int attr_done = 0;  // host-side only; idempotent attribute, not kernel state
  if (!attr_done) {
    hipFuncSetAttribute((const void*)attnpool_kernel,
                        hipFuncAttributeMaxDynamicSharedMemorySize, SMEM_BYTES);
    attr_done = 1;
  }

  const int ntiles = (N + TROWS - 1) / TROWS;
  const int base = ntiles / NBLOCKS;
  const int rem = ntiles % NBLOCKS;

  hipMemsetAsync(d_out, 0, (size_t)out_size * sizeof(float), stream);
  hipMemsetAsync(Zp, 0, sizeof(float), stream);
  prep_w1_kernel<<<128, 64, 0, stream>>>(W1, W1f);
  attnpool_kernel<<<NBLOCKS, 512, SMEM_BYTES, stream>>>(x, batch, W1f, b1, W2, b2,
                                                        out, Zp, N, base, rem);
  finalize_kernel<<<(out_size / 4 + 255) / 256, 256, 0, stream>>>(out, Zp, out_size / 4);
}

// Round 16
// 224.582 us; speedup vs baseline: 1.2423x; 1.2423x over previous
//
#include <hip/hip_runtime.h>
#include <stdint.h>

#define NBLOCKS 256
#define TROWS 64
#define B_FRAGS 126                       // frags 126,127 stream from L2 (2 only)
#define XT_OFF (B_FRAGS * 1024)           // 129024
#define SPART_OFF (XT_OFF + 32768)        // 161792
#define SMEM_BYTES (SPART_OFF + 1024)     // 162816 <= 163840

typedef __attribute__((ext_vector_type(8))) short bfrag_t;
typedef __attribute__((ext_vector_type(4))) float f32x4;
typedef __attribute__((ext_vector_type(2))) unsigned int u32x2;

static __device__ __forceinline__ unsigned short f2bf(float f) {
  unsigned int u = __float_as_uint(f);
  u += 0x7fffu + ((u >> 16) & 1u);   // RNE
  return (unsigned short)(u >> 16);
}

static __device__ __forceinline__ float tanh_fast(float s) {
  float e = __builtin_exp2f(s * 2.8853900817779268f);
  float r = __builtin_amdgcn_rcpf(1.f + e);
  return __builtin_fmaf(-2.f, r, 1.f);
}

// readlane for floats: BIT-cast (int builtin; float would value-truncate — r4 bug)
static __device__ __forceinline__ float readlane_f(float v, int l) {
  return __uint_as_float(__builtin_amdgcn_readlane(__float_as_uint(v), l));
}

static __device__ __forceinline__ bfrag_t pack8(f32x4 a, f32x4 b) {
  union { bfrag_t v; unsigned int u[4]; } r;
  asm("v_cvt_pk_bf16_f32 %0, %1, %2" : "=v"(r.u[0]) : "v"(a[0]), "v"(a[1]));
  asm("v_cvt_pk_bf16_f32 %0, %1, %2" : "=v"(r.u[1]) : "v"(a[2]), "v"(a[3]));
  asm("v_cvt_pk_bf16_f32 %0, %1, %2" : "=v"(r.u[2]) : "v"(b[0]), "v"(b[1]));
  asm("v_cvt_pk_bf16_f32 %0, %1, %2" : "=v"(r.u[3]) : "v"(b[2]), "v"(b[3]));
  return r.v;
}

#define GLD16(gp, lp) __builtin_amdgcn_global_load_lds( \
    (const __attribute__((address_space(1))) void*)(gp), \
    (__attribute__((address_space(3))) void*)(lp), 16, 0, 0)

// raw barrier draining LDS ops only; global reg-loads stay in flight
#define BAR_LGKM() do { \
  asm volatile("s_waitcnt lgkmcnt(0)" ::: "memory"); \
  __builtin_amdgcn_s_barrier(); \
  asm volatile("" ::: "memory"); } while (0)

// Pre-swizzle W1 (f32 [256][256], k-major) into MFMA B-fragment order, bf16.
// W1f[((cc*8+kk)*64 + lane)*8 + j] = bf16(W1[kk*32 + 8*(lane>>4) + j][cc*16 + (lane&15)])
__global__ void prep_w1_kernel(const float* __restrict__ W1, unsigned short* __restrict__ W1f) {
  const int bx = blockIdx.x;   // cc*8 + kk, 0..127
  const int l = threadIdx.x;   // 0..63
  const int cc = bx >> 3, kk = bx & 7;
  const int h = cc * 16 + (l & 15);
  const int kbase = kk * 32 + ((l >> 4) << 3);
  bfrag_t pk;
#pragma unroll
  for (int j = 0; j < 8; ++j) pk[j] = (short)f2bf(W1[(size_t)(kbase + j) * 256 + h]);
  *(bfrag_t*)(W1f + (size_t)(bx * 64 + l) * 8) = pk;
}

__attribute__((amdgpu_flat_work_group_size(512, 512), amdgpu_waves_per_eu(2, 2)))
__global__ void attnpool_kernel(const float* __restrict__ x,
                                const int* __restrict__ batch,
                                const unsigned short* __restrict__ W1f,
                                const float* __restrict__ b1,
                                const float* __restrict__ W2,
                                const float* __restrict__ b2,
                                float* __restrict__ out,   // raw weighted sums (zeroed)
                                float* __restrict__ Zp,    // softmax denominator (zeroed)
                                int N, int base, int rem) {
  extern __shared__ char smem[];
  char* Bl = smem;                           // B frags 0..125, frag-linear
  char* xt = smem + XT_OFF;                  // [64 rows][512B] bf16 tile, swizzled
  float* spart = (float*)(smem + SPART_OFF); // [4 cgr][64 rows]

  const int t = threadIdx.x;
  const int lane = t & 63;
  const int wv = t >> 6;        // 0..7
  const int rg = wv & 1;        // row half: rows rg*32..+31
  const int cgr = wv >> 1;      // cc quad: cc cgr*4..+3
  const int l15 = lane & 15;
  const int hi = lane >> 4;

  const int blk = blockIdx.x;
  const int cnt = base + (blk < rem ? 1 : 0);
  const int tile0 = blk * base + min(blk, rem);

  // ---- B -> LDS (frag-linear via GLD16; frags 126,127 stay in L2) ----
#pragma unroll
  for (int i = 0; i < 16; ++i) {
    const int f = wv * 16 + i;
    if (f < B_FRAGS) GLD16(W1f + (size_t)f * 512 + lane * 8, Bl + f * 1024);
  }

  // per-lane constants for my 4 cc's
  float b1v[4], w2v[4];
#pragma unroll
  for (int c = 0; c < 4; ++c) {
    b1v[c] = b1[(cgr * 4 + c) * 16 + l15];
    w2v[c] = W2[(cgr * 4 + c) * 16 + l15];
  }
  const float b2c = b2[0];

  // ---- cooperative 2-deep reg staging: 512 threads stage 64 rows ----
  const int srow = t >> 5;    // 0..15
  const int soct = t & 31;
  f32x4 sA[8], sB[8];
  auto issue_loads = [&](int tile, f32x4 (&sreg)[8]) {
#pragma unroll
    for (int p = 0; p < 4; ++p) {
      const int row = p * 16 + srow;
      const int rgb = min(tile * TROWS + row, N - 1);
      const float* s = x + (size_t)rgb * 256 + soct * 8;
      sreg[2 * p] = *(const f32x4*)s;
      sreg[2 * p + 1] = *(const f32x4*)(s + 4);
    }
  };
  auto write_tile = [&](f32x4 (&sreg)[8]) {
#pragma unroll
    for (int p = 0; p < 4; ++p) {
      const int row = p * 16 + srow;
      *(bfrag_t*)(xt + row * 512 + ((soct * 16) ^ ((row & 7) << 4))) =
          pack8(sreg[2 * p], sreg[2 * p + 1]);
    }
  };

  float zacc = 0.f;
  f32x4 pacc = {0.f, 0.f, 0.f, 0.f};
  int gcur = -1;

  auto flush = [&]() {
    float* po = out + (size_t)gcur * 256 + lane * 4;
    atomicAdd(po + 0, pacc[0]); atomicAdd(po + 1, pacc[1]);
    atomicAdd(po + 2, pacc[2]); atomicAdd(po + 3, pacc[3]);
    pacc[0] = pacc[1] = pacc[2] = pacc[3] = 0.f;
  };

  // body(t): xt holds tile t; sWr holds tile t+1 (issued one body ago);
  // issues tile t+2 into sIss (in flight across the whole body).
  auto body = [&](int tt, f32x4 (&sIss)[8], f32x4 (&sWr)[8]) {
    const int tile = tile0 + tt;
    const int R0 = tile * TROWS;

    if (tt + 2 < cnt) issue_loads(tile + 2, sIss);

    // ---- score: kk-outer; one B-read feeds 32 rows (A0,A1) ----
    f32x4 acc[4][2] = {};
    const int arow0 = rg * 32 + l15;
    const int sw = (l15 & 7) << 4;             // (arow0+16)&7 == arow0&7
#pragma unroll
    for (int kk = 0; kk < 8; ++kk) {
      const int co = (kk * 64 + hi * 16) ^ sw;
      const bfrag_t A0 = *(const bfrag_t*)(xt + arow0 * 512 + co);
      const bfrag_t A1 = *(const bfrag_t*)(xt + (arow0 + 16) * 512 + co);
#pragma unroll
      for (int c = 0; c < 4; ++c) {
        const int frag = (cgr * 4 + c) * 8 + kk;
        bfrag_t Bk;
        if (frag < B_FRAGS)    // wave-uniform branch; false only for frags 126,127
          Bk = *(const bfrag_t*)(Bl + frag * 1024 + lane * 16);
        else
          Bk = *(const bfrag_t*)(W1f + (size_t)frag * 512 + lane * 8);
        acc[c][0] = __builtin_amdgcn_mfma_f32_16x16x32_bf16(A0, Bk, acc[c][0], 0, 0, 0);
        acc[c][1] = __builtin_amdgcn_mfma_f32_16x16x32_bf16(A1, Bk, acc[c][1], 0, 0, 0);
      }
    }

    // ---- tanh epilogue + 16-lane reduce; partial for my cc-quad ----
    float s0v[4] = {0.f, 0.f, 0.f, 0.f};
    float s1v[4] = {0.f, 0.f, 0.f, 0.f};
#pragma unroll
    for (int c = 0; c < 4; ++c)
#pragma unroll
      for (int r = 0; r < 4; ++r) {
        s0v[r] += tanh_fast(acc[c][0][r] + b1v[c]) * w2v[c];
        s1v[r] += tanh_fast(acc[c][1][r] + b1v[c]) * w2v[c];
      }
#pragma unroll
    for (int r = 0; r < 4; ++r) {
      float v0 = s0v[r], v1 = s1v[r];
      v0 += __shfl_xor(v0, 1); v0 += __shfl_xor(v0, 2);
      v0 += __shfl_xor(v0, 4); v0 += __shfl_xor(v0, 8);
      v1 += __shfl_xor(v1, 1); v1 += __shfl_xor(v1, 2);
      v1 += __shfl_xor(v1, 4); v1 += __shfl_xor(v1, 8);
      s0v[r] = v0; s1v[r] = v1;
    }
    if (l15 == 0) {
#pragma unroll
      for (int r = 0; r < 4; ++r) {
        spart[cgr * 64 + rg * 32 + hi * 4 + r] = s0v[r];
        spart[cgr * 64 + rg * 32 + 16 + hi * 4 + r] = s1v[r];
      }
    }
    BAR_LGKM();   // SYNC1: all 4 partials visible (global loads stay in flight)

    // ---- w for my pool rows (wv*8..+7): sum 4 partials, exp ----
    const int prow = wv * 8 + (lane & 7);
    float wlane;
    {
      float v = spart[((lane >> 3) & 3) * 64 + prow];
      v += __shfl_xor(v, 8);
      v += __shfl_xor(v, 16);
      wlane = (R0 + prow < N) ? __expf(v + b2c) : 0.f;
    }
    {
      float zv = (lane < 8) ? wlane : 0.f;
      zv += __shfl_xor(zv, 1);  zv += __shfl_xor(zv, 2);  zv += __shfl_xor(zv, 4);
      zv += __shfl_xor(zv, 8);  zv += __shfl_xor(zv, 16); zv += __shfl_xor(zv, 32);
      zacc += zv;
    }
    int bid = batch[min(R0 + prow, N - 1)];

    // ---- pool my 8 rows from xt; lane owns bf16 cols 4*lane..+3 ----
    const int g_first = __builtin_amdgcn_readlane(bid, 0);
    const int g_last = __builtin_amdgcn_readlane(bid, 7);
    if (g_first != gcur) { if (gcur >= 0) flush(); gcur = g_first; }
    const int rowb = wv * 8;
    if (g_first == g_last) {
#pragma unroll
      for (int r = 0; r < 8; ++r) {
        const float wr = readlane_f(wlane, r);
        const int row = rowb + r;
        const u32x2 v = *(const u32x2*)(xt + row * 512 + ((lane * 8) ^ ((row & 7) << 4)));
        pacc[0] = __builtin_fmaf(wr, __uint_as_float(v[0] << 16), pacc[0]);
        pacc[1] = __builtin_fmaf(wr, __uint_as_float(v[0] & 0xffff0000u), pacc[1]);
        pacc[2] = __builtin_fmaf(wr, __uint_as_float(v[1] << 16), pacc[2]);
        pacc[3] = __builtin_fmaf(wr, __uint_as_float(v[1] & 0xffff0000u), pacc[3]);
      }
    } else {
      for (int r = 0; r < 8; ++r) {
        const int g = __builtin_amdgcn_readlane(bid, r);
        if (g != gcur) { flush(); gcur = g; }
        const float wr = readlane_f(wlane, r);
        const int row = rowb + r;
        const u32x2 v = *(const u32x2*)(xt + row * 512 + ((lane * 8) ^ ((row & 7) << 4)));
        pacc[0] = __builtin_fmaf(wr, __uint_as_float(v[0] << 16), pacc[0]);
        pacc[1] = __builtin_fmaf(wr, __uint_as_float(v[0] & 0xffff0000u), pacc[1]);
        pacc[2] = __builtin_fmaf(wr, __uint_as_float(v[1] << 16), pacc[2]);
        pacc[3] = __builtin_fmaf(wr, __uint_as_float(v[1] & 0xffff0000u), pacc[3]);
      }
    }

    BAR_LGKM();                          // SYNC2: all reads of tile t retired
    if (tt + 1 < cnt) write_tile(sWr);   // counted vmcnt via reg dep; t+2 in flight
    BAR_LGKM();                          // SYNC3: tile t+1 visible
  };

  // ---- prologue ----
  issue_loads(tile0, sA);
  write_tile(sA);                      // implicit vmcnt wait also drains B's GLD16s
  if (cnt > 1) issue_loads(tile0 + 1, sB);
  BAR_LGKM();                          // B + tile0 visible

  int tt = 0;
  for (;;) {
    body(tt, sA, sB);
    if (++tt >= cnt) break;
    body(tt, sB, sA);
    if (++tt >= cnt) break;
  }

  if (gcur >= 0) flush();
  if (lane == 0 && zacc != 0.f) atomicAdd(Zp, zacc);
}

__global__ void finalize_kernel(float* __restrict__ out, const float* __restrict__ Zp, int n4) {
  const int i = blockIdx.x * blockDim.x + threadIdx.x;
  if (i < n4) {
    const float zi = 1.f / Zp[0];
    f32x4* p = (f32x4*)out;
    f32x4 v = p[i];
    v[0] *= zi; v[1] *= zi; v[2] *= zi; v[3] *= zi;
    p[i] = v;
  }
}

extern "C" void kernel_launch(void* const* d_in, const int* in_sizes, int n_in,
                              void* d_out, int out_size, void* d_ws, size_t ws_size,
                              hipStream_t stream) {
  const float* x  = (const float*)d_in[0];
  const int* batch = (const int*)d_in[1];
  const float* W1 = (const float*)d_in[2];
  const float* b1 = (const float*)d_in[3];
  const float* W2 = (const float*)d_in[4];
  const float* b2 = (const float*)d_in[5];
  float* out = (float*)d_out;
  const int N = in_sizes[1];

  unsigned short* W1f = (unsigned short*)d_ws;          // 128 KB
  float* Zp = (float*)((char*)d_ws + 131072);           // 4 B

  static int attr_done = 0;  // host-side only; idempotent attribute, not kernel state
  if (!attr_done) {
    hipFuncSetAttribute((const void*)attnpool_kernel,
                        hipFuncAttributeMaxDynamicSharedMemorySize, SMEM_BYTES);
    attr_done = 1;
  }

  const int ntiles = (N + TROWS - 1) / TROWS;
  const int base = ntiles / NBLOCKS;
  const int rem = ntiles % NBLOCKS;

  hipMemsetAsync(d_out, 0, (size_t)out_size * sizeof(float), stream);
  hipMemsetAsync(Zp, 0, sizeof(float), stream);
  prep_w1_kernel<<<128, 64, 0, stream>>>(W1, W1f);
  attnpool_kernel<<<NBLOCKS, 512, SMEM_BYTES, stream>>>(x, batch, W1f, b1, W2, b2,
                                                        out, Zp, N, base, rem);
  finalize_kernel<<<(out_size / 4 + 255) / 256, 256, 0, stream>>>(out, Zp, out_size / 4);
}